// Round 1
// 1813.474 us; speedup vs baseline: 3.4409x; 3.4409x over previous
//
#include <hip/hip_runtime.h>
#include <hip/hip_bf16.h>

typedef __hip_bfloat16 bf16;
typedef unsigned short u16;
typedef __attribute__((ext_vector_type(8))) short bf16x8;
typedef __attribute__((ext_vector_type(4))) float f32x4;

__device__ __forceinline__ float b2f(bf16 v) { return __bfloat162float(v); }
__device__ __forceinline__ float b2f_u(u16 h) {
    union { unsigned u; float f; } c; c.u = ((unsigned)h) << 16; return c.f;
}
__device__ __forceinline__ u16 f2b(float v) {
    union { bf16 b; u16 u; } c; c.b = __float2bfloat16(v); return c.u;
}
__device__ __forceinline__ float lrelu(float v) { return v >= 0.f ? v : 0.2f * v; }
__device__ __forceinline__ float ldin(const void* p, size_t i, int isbf) {
    if (isbf) return b2f(((const bf16*)p)[i]);
    return ((const float*)p)[i];
}
// LDS tile layout: [pixel][64 ci] bf16, 128B row = 8 x 16B chunks, XOR-swizzled
// by pixel so ds_read_b128 B-fragments (16 consecutive pixels per 16-lane group)
// are bank-conflict-free.
__device__ __forceinline__ int swz_hw(int pl, int ci) {
    return pl * 64 + (((ci >> 3) ^ (pl & 7)) << 3) + (ci & 7);
}
__device__ __forceinline__ bf16x8 frag(const u16* t, int pl, int chunk) {
    return *(const bf16x8*)(t + pl * 64 + ((chunk ^ (pl & 7)) << 3));
}

// ---------------------------------------------------------------------------
// Probe: bf16 vs fp32 input detection (unchanged).
// ---------------------------------------------------------------------------
__global__ __launch_bounds__(256)
void probe_kernel(const void* __restrict__ x, int* __restrict__ flag) {
    const int tid = threadIdx.x;
    __shared__ int bad;
    if (tid == 0) bad = 0;
    __syncthreads();
    const unsigned short* h = (const unsigned short*)x;
    for (int k = tid; k < 512; k += 256) {
        const unsigned e = (h[k] >> 7) & 0xFFu;
        if (e < 100u || e > 140u) atomicAdd(&bad, 1);
    }
    __syncthreads();
    if (tid == 0) flag[0] = (bad == 0) ? 1 : 0;
}

// ---------------------------------------------------------------------------
// Weights: styles + demod, then effective weights as bf16 hi/lo pairs in
// MFMA-A layout [b][tap][oc][ci] (ci contiguous).
// ---------------------------------------------------------------------------
__global__ __launch_bounds__(256)
void weights_kernel(const void* __restrict__ s,
                    const void* __restrict__ a1w, const void* __restrict__ a1b,
                    const void* __restrict__ w1,
                    const void* __restrict__ a2w, const void* __restrict__ a2b,
                    const void* __restrict__ w2,
                    const void* __restrict__ scw_in,
                    u16* __restrict__ w1h, u16* __restrict__ w1l,
                    u16* __restrict__ w2h, u16* __restrict__ w2l,
                    u16* __restrict__ sch, u16* __restrict__ scl,
                    const int* __restrict__ flag) {
    const int isbf = flag[0];
    const int b = blockIdx.x;
    const int part = blockIdx.y;   // 0..3: quarter of the weight writes
    const int tid = threadIdx.x;
    __shared__ float sb[64];
    __shared__ float st1[64];
    __shared__ float st2[128];
    __shared__ float d1[128];
    __shared__ float d2[128];

    if (tid < 64) sb[tid] = ldin(s, b * 64 + tid, isbf);
    __syncthreads();

    if (tid < 64) {
        float a = ldin(a1b, tid, isbf) + 1.f;
        for (int j = 0; j < 64; ++j) a += sb[j] * ldin(a1w, tid * 64 + j, isbf);
        st1[tid] = a;
    }
    if (tid >= 128) {
        const int i = tid - 128;
        float a = ldin(a2b, i, isbf) + 1.f;
        for (int j = 0; j < 64; ++j) a += sb[j] * ldin(a2w, i * 64 + j, isbf);
        st2[i] = a;
    }
    __syncthreads();

    if (tid < 128) {
        float acc = 0.f;
        for (int i = 0; i < 64; ++i) {
            const float st = st1[i];
            for (int t = 0; t < 9; ++t) {
                const float v = ldin(w1, (tid * 64 + i) * 9 + t, isbf) * st;
                acc += v * v;
            }
        }
        d1[tid] = rsqrtf(acc + 1e-8f);
    } else {
        const int o = tid - 128;
        float acc = 0.f;
        for (int i = 0; i < 128; ++i) {
            const float st = st2[i];
            for (int t = 0; t < 9; ++t) {
                const float v = ldin(w2, (o * 128 + i) * 9 + t, isbf) * st;
                acc += v * v;
            }
        }
        d2[o] = rsqrtf(acc + 1e-8f);
    }
    __syncthreads();

    // w1eff: [8][9][128 oc][64 ci], hi/lo
    for (int idx = part * 18432 + tid; idx < (part + 1) * 18432; idx += 256) {
        const int o = idx / 576;
        const int r = idx - o * 576;
        const int i = r / 9;
        const int t = r - i * 9;
        const float w = ldin(w1, idx, isbf) * st1[i] * d1[o];
        const u16 h = f2b(w);
        const size_t dst = ((size_t)(b * 9 + t) * 128 + o) * 64 + i;
        w1h[dst] = h;
        w1l[dst] = f2b(w - b2f_u(h));
    }
    // w2eff: [8][9][128 oc][128 ci], hi/lo
    for (int idx = part * 36864 + tid; idx < (part + 1) * 36864; idx += 256) {
        const int o = idx / 1152;
        const int r = idx - o * 1152;
        const int i = r / 9;
        const int t = r - i * 9;
        const float w = ldin(w2, idx, isbf) * st2[i] * d2[o];
        const u16 h = f2b(w);
        const size_t dst = ((size_t)(b * 9 + t) * 128 + o) * 128 + i;
        w2h[dst] = h;
        w2l[dst] = f2b(w - b2f_u(h));
    }
    // shortcut weights [128 oc][64 ci] hi/lo (input layout already [o][i])
    if (b == 0 && part == 0) {
        for (int idx = tid; idx < 8192; idx += 256) {
            const float w = ldin(scw_in, idx, isbf);
            const u16 h = f2b(w);
            sch[idx] = h;
            scl[idx] = f2b(w - b2f_u(h));
        }
    }
}

// ---------------------------------------------------------------------------
// Conv1 (MFMA): h1 = lrelu(conv3x3(lrelu(x), w1eff) + nw*noise) -> bf16,
// stored transposed [b][y][x][128] for conv2.
// Block: 256 thr = 4 waves (2 oc x 2 row-halves), 8x16 px tile, all 128 oc.
// X split hi/lo (fp32 mode) + W split hi/lo => near-fp32 accumulation.
// ---------------------------------------------------------------------------
__global__ __launch_bounds__(256, 3)
void conv1_mfma(const void* __restrict__ x, const void* __restrict__ noise,
                const void* __restrict__ nwp,
                const u16* __restrict__ w1h, const u16* __restrict__ w1l,
                u16* __restrict__ h1t, const int* __restrict__ flag) {
    __shared__ u16 tH[180 * 64];
    __shared__ u16 tL[180 * 64];
    const int isbf = flag[0];
    const int b = blockIdx.z;
    const int gx0 = blockIdx.x << 4, gy0 = blockIdx.y << 3;
    const int tid = threadIdx.x;

    // Stage lrelu(x): transpose [ci][y][x] -> [pl][ci] bf16 hi/lo, swizzled.
    for (int task = tid; task < 640; task += 256) {
        const int ci = task / 10;
        const int r = task - ci * 10;           // tile row 0..9
        const int gy = gy0 - 1 + r;
        const int rv = ((unsigned)gy < 256u);
        const size_t rb = (((size_t)b * 64 + ci) << 16) + ((size_t)(gy & 255) << 8);
#pragma unroll 1
        for (int c = 0; c < 18; ++c) {
            const int gx = gx0 - 1 + c;
            float v = 0.f;
            if (rv && (unsigned)gx < 256u) v = ldin(x, rb + gx, isbf);
            v = lrelu(v);
            const u16 h = f2b(v);
            const int hw = swz_hw(r * 18 + c, ci);
            tH[hw] = h;
            if (!isbf) tL[hw] = f2b(v - b2f_u(h));
        }
    }
    __syncthreads();

    const int lane = tid & 63;
    const int wv = tid >> 6;
    const int wm = wv >> 1, wn = wv & 1;
    const int l15 = lane & 15, g = lane >> 4;

    f32x4 acc[4][4];
#pragma unroll
    for (int i = 0; i < 4; ++i)
#pragma unroll
        for (int j = 0; j < 4; ++j) acc[i][j] = (f32x4){0.f, 0.f, 0.f, 0.f};

    const u16* aH = w1h + (size_t)b * 73728 + (wm * 64 + l15) * 64 + g * 8;
    const u16* aL = w1l + (size_t)b * 73728 + (wm * 64 + l15) * 64 + g * 8;
    const int plb = wn * 72 + l15;

#pragma unroll 1
    for (int kh = 0; kh < 3; ++kh) {
#pragma unroll
        for (int kw = 0; kw < 3; ++kw) {
            const int t = kh * 3 + kw;
            const u16* at = aH + t * 8192;
            const u16* atl = aL + t * 8192;
#pragma unroll
            for (int cs = 0; cs < 2; ++cs) {
                bf16x8 bh[4], bl[4];
#pragma unroll
                for (int fn = 0; fn < 4; ++fn) {
                    const int pl = plb + (fn + kh) * 18 + kw;
                    bh[fn] = frag(tH, pl, cs * 4 + g);
                }
                if (!isbf) {
#pragma unroll
                    for (int fn = 0; fn < 4; ++fn) {
                        const int pl = plb + (fn + kh) * 18 + kw;
                        bl[fn] = frag(tL, pl, cs * 4 + g);
                    }
                }
#pragma unroll
                for (int fm = 0; fm < 4; ++fm) {
                    const bf16x8 ah = *(const bf16x8*)(at + fm * 1024 + cs * 32);
                    const bf16x8 al = *(const bf16x8*)(atl + fm * 1024 + cs * 32);
#pragma unroll
                    for (int fn = 0; fn < 4; ++fn)
                        acc[fm][fn] = __builtin_amdgcn_mfma_f32_16x16x32_bf16(ah, bh[fn], acc[fm][fn], 0, 0, 0);
#pragma unroll
                    for (int fn = 0; fn < 4; ++fn)
                        acc[fm][fn] = __builtin_amdgcn_mfma_f32_16x16x32_bf16(al, bh[fn], acc[fm][fn], 0, 0, 0);
                    if (!isbf) {
#pragma unroll
                        for (int fn = 0; fn < 4; ++fn)
                            acc[fm][fn] = __builtin_amdgcn_mfma_f32_16x16x32_bf16(ah, bl[fn], acc[fm][fn], 0, 0, 0);
                    }
                }
            }
        }
    }

    const float nwv = ldin(nwp, 0, isbf);
#pragma unroll
    for (int fn = 0; fn < 4; ++fn) {
        const int gy = gy0 + wn * 4 + fn;
        const int gx = gx0 + l15;
        const float nv = nwv * ldin(noise, ((size_t)b << 16) + (gy << 8) + gx, isbf);
        u16* dst = h1t + ((((size_t)b << 16) + (gy << 8) + gx) << 7) + wm * 64 + g * 4;
#pragma unroll
        for (int fm = 0; fm < 4; ++fm) {
            const unsigned lo = (unsigned)f2b(lrelu(acc[fm][fn][0] + nv)) |
                                ((unsigned)f2b(lrelu(acc[fm][fn][1] + nv)) << 16);
            const unsigned hi = (unsigned)f2b(lrelu(acc[fm][fn][2] + nv)) |
                                ((unsigned)f2b(lrelu(acc[fm][fn][3] + nv)) << 16);
            *(uint2*)(dst + fm * 16) = make_uint2(lo, hi);
        }
    }
}

// ---------------------------------------------------------------------------
// Conv2 (MFMA): conv3x3(h1, w2eff) + 1x1 shortcut (folded as extra K-chunks)
// + noise, * 1/sqrt(2).
// ---------------------------------------------------------------------------
__global__ __launch_bounds__(256, 3)
void conv2_mfma(const u16* __restrict__ h1t, const void* __restrict__ x,
                const void* __restrict__ noise, const void* __restrict__ nwp,
                const u16* __restrict__ w2h, const u16* __restrict__ w2l,
                const u16* __restrict__ sch, const u16* __restrict__ scl,
                void* __restrict__ out, const int* __restrict__ flag) {
    __shared__ u16 tA[180 * 64];
    __shared__ u16 tB[180 * 64];
    const int isbf = flag[0];
    const int b = blockIdx.z;
    const int gx0 = blockIdx.x << 4, gy0 = blockIdx.y << 3;
    const int tid = threadIdx.x;
    const int lane = tid & 63;
    const int wv = tid >> 6;
    const int wm = wv >> 1, wn = wv & 1;
    const int l15 = lane & 15, g = lane >> 4;

    // Stage both 64-ci chunks of h1 (tile [10][18][64] each, swizzled).
    const bf16x8 z8 = {0, 0, 0, 0, 0, 0, 0, 0};
#pragma unroll 1
    for (int cc = 0; cc < 2; ++cc) {
        u16* tile = cc ? tB : tA;
        for (int idx = tid; idx < 1440; idx += 256) {
            const int pl = idx >> 3, c = idx & 7;
            const int row = pl / 18, col = pl - row * 18;
            const int gy = gy0 - 1 + row, gx = gx0 - 1 + col;
            bf16x8 v = z8;
            if ((unsigned)gy < 256u && (unsigned)gx < 256u)
                v = *(const bf16x8*)(h1t + ((((size_t)b << 16) + (gy << 8) + gx) << 7) + cc * 64 + c * 8);
            *(bf16x8*)(tile + pl * 64 + ((c ^ (pl & 7)) << 3)) = v;
        }
    }
    __syncthreads();

    f32x4 acc[4][4];
#pragma unroll
    for (int i = 0; i < 4; ++i)
#pragma unroll
        for (int j = 0; j < 4; ++j) acc[i][j] = (f32x4){0.f, 0.f, 0.f, 0.f};

    const int plb = wn * 72 + l15;
    const size_t abase = (size_t)b * 147456 + (wm * 64 + l15) * 128 + g * 8;

#pragma unroll 1
    for (int cc = 0; cc < 2; ++cc) {
        const u16* tile = cc ? tB : tA;
        const u16* aH = w2h + abase + cc * 64;
        const u16* aL = w2l + abase + cc * 64;
#pragma unroll 1
        for (int kh = 0; kh < 3; ++kh) {
#pragma unroll
            for (int kw = 0; kw < 3; ++kw) {
                const int t = kh * 3 + kw;
                const u16* at = aH + t * 16384;
                const u16* atl = aL + t * 16384;
#pragma unroll
                for (int cs = 0; cs < 2; ++cs) {
                    bf16x8 bh[4];
#pragma unroll
                    for (int fn = 0; fn < 4; ++fn) {
                        const int pl = plb + (fn + kh) * 18 + kw;
                        bh[fn] = frag(tile, pl, cs * 4 + g);
                    }
#pragma unroll
                    for (int fm = 0; fm < 4; ++fm) {
                        const bf16x8 ah = *(const bf16x8*)(at + fm * 2048 + cs * 32);
                        const bf16x8 al = *(const bf16x8*)(atl + fm * 2048 + cs * 32);
#pragma unroll
                        for (int fn = 0; fn < 4; ++fn)
                            acc[fm][fn] = __builtin_amdgcn_mfma_f32_16x16x32_bf16(ah, bh[fn], acc[fm][fn], 0, 0, 0);
#pragma unroll
                        for (int fn = 0; fn < 4; ++fn)
                            acc[fm][fn] = __builtin_amdgcn_mfma_f32_16x16x32_bf16(al, bh[fn], acc[fm][fn], 0, 0, 0);
                    }
                }
            }
        }
    }
    __syncthreads();

    // Shortcut: stage raw x (no halo, [8][16][64], hi/lo) and run 1x1 as GEMM.
    for (int task = tid; task < 512; task += 256) {
        const int ci = task >> 3;
        const int r = task & 7;
        const int gy = gy0 + r;
        const size_t rb = (((size_t)b * 64 + ci) << 16) + ((size_t)gy << 8) + gx0;
#pragma unroll 1
        for (int c = 0; c < 16; ++c) {
            const float v = ldin(x, rb + c, isbf);
            const u16 h = f2b(v);
            const int hw = swz_hw(r * 16 + c, ci);
            tA[hw] = h;
            if (!isbf) tB[hw] = f2b(v - b2f_u(h));
        }
    }
    __syncthreads();

    const u16* sH = sch + (wm * 64 + l15) * 64 + g * 8;
    const u16* sL = scl + (wm * 64 + l15) * 64 + g * 8;
#pragma unroll
    for (int cs = 0; cs < 2; ++cs) {
        bf16x8 bh[4], bl[4];
#pragma unroll
        for (int fn = 0; fn < 4; ++fn) {
            const int pl = (wn * 4 + fn) * 16 + l15;
            bh[fn] = frag(tA, pl, cs * 4 + g);
        }
        if (!isbf) {
#pragma unroll
            for (int fn = 0; fn < 4; ++fn) {
                const int pl = (wn * 4 + fn) * 16 + l15;
                bl[fn] = frag(tB, pl, cs * 4 + g);
            }
        }
#pragma unroll
        for (int fm = 0; fm < 4; ++fm) {
            const bf16x8 ah = *(const bf16x8*)(sH + fm * 1024 + cs * 32);
            const bf16x8 al = *(const bf16x8*)(sL + fm * 1024 + cs * 32);
#pragma unroll
            for (int fn = 0; fn < 4; ++fn)
                acc[fm][fn] = __builtin_amdgcn_mfma_f32_16x16x32_bf16(ah, bh[fn], acc[fm][fn], 0, 0, 0);
#pragma unroll
            for (int fn = 0; fn < 4; ++fn)
                acc[fm][fn] = __builtin_amdgcn_mfma_f32_16x16x32_bf16(al, bh[fn], acc[fm][fn], 0, 0, 0);
            if (!isbf) {
#pragma unroll
                for (int fn = 0; fn < 4; ++fn)
                    acc[fm][fn] = __builtin_amdgcn_mfma_f32_16x16x32_bf16(ah, bl[fn], acc[fm][fn], 0, 0, 0);
            }
        }
    }

    const float nwv = ldin(nwp, 0, isbf);
    const float kk = 0.70710678118654752f;
    if (isbf) {
        bf16* op = (bf16*)out;
#pragma unroll
        for (int fn = 0; fn < 4; ++fn) {
            const int gy = gy0 + wn * 4 + fn;
            const int gx = gx0 + l15;
            const float nv = nwv * ldin(noise, ((size_t)b << 16) + (gy << 8) + gx, isbf);
#pragma unroll
            for (int fm = 0; fm < 4; ++fm) {
                const int oc = wm * 64 + fm * 16 + g * 4;
#pragma unroll
                for (int r = 0; r < 4; ++r) {
                    const float v = (acc[fm][fn][r] + nv) * kk;
                    op[(((size_t)b * 128 + oc + r) << 16) + (gy << 8) + gx] = __float2bfloat16(v);
                }
            }
        }
    } else {
        float* op = (float*)out;
#pragma unroll
        for (int fn = 0; fn < 4; ++fn) {
            const int gy = gy0 + wn * 4 + fn;
            const int gx = gx0 + l15;
            const float nv = nwv * ldin(noise, ((size_t)b << 16) + (gy << 8) + gx, isbf);
#pragma unroll
            for (int fm = 0; fm < 4; ++fm) {
                const int oc = wm * 64 + fm * 16 + g * 4;
#pragma unroll
                for (int r = 0; r < 4; ++r) {
                    const float v = (acc[fm][fn][r] + nv) * kk;
                    op[(((size_t)b * 128 + oc + r) << 16) + (gy << 8) + gx] = v;
                }
            }
        }
    }
}

extern "C" void kernel_launch(void* const* d_in, const int* in_sizes, int n_in,
                              void* d_out, int out_size, void* d_ws, size_t ws_size,
                              hipStream_t stream) {
    const void* x     = d_in[0];
    const void* s     = d_in[1];
    const void* noise = d_in[2];
    const void* a1w   = d_in[3];
    const void* a1b   = d_in[4];
    const void* w1    = d_in[5];
    const void* a2w   = d_in[6];
    const void* a2b   = d_in[7];
    const void* w2    = d_in[8];
    const void* nw    = d_in[9];
    const void* scw   = d_in[10];

    // ws layout (bytes):
    //   flag   256
    //   w1h/w1l  2 x 1,179,648   ([8][9][128][64] bf16)
    //   w2h/w2l  2 x 2,359,296   ([8][9][128][128] bf16)
    //   sch/scl  2 x 16,384      ([128][64] bf16)
    //   h1t      134,217,728     ([8][256][256][128] bf16, y/x-major)
    //   total ~141.3 MB (same footprint as previous version)
    char* p = (char*)d_ws;
    int* flag = (int*)p;            p += 256;
    u16* w1h = (u16*)p;             p += 1179648;
    u16* w1l = (u16*)p;             p += 1179648;
    u16* w2h = (u16*)p;             p += 2359296;
    u16* w2l = (u16*)p;             p += 2359296;
    u16* sch = (u16*)p;             p += 16384;
    u16* scl = (u16*)p;             p += 16384;
    u16* h1t = (u16*)p;

    probe_kernel<<<dim3(1), dim3(256), 0, stream>>>(x, flag);
    weights_kernel<<<dim3(8, 4), dim3(256), 0, stream>>>(s, a1w, a1b, w1, a2w, a2b, w2,
                                                         scw, w1h, w1l, w2h, w2l,
                                                         sch, scl, flag);
    dim3 grid(16, 32, 8);
    conv1_mfma<<<grid, dim3(256), 0, stream>>>(x, noise, nw, w1h, w1l, h1t, flag);
    conv2_mfma<<<grid, dim3(256), 0, stream>>>(h1t, x, noise, nw, w2h, w2l, sch, scl,
                                               d_out, flag);
}

// Round 2
// 1670.900 us; speedup vs baseline: 3.7345x; 1.0853x over previous
//
#include <hip/hip_runtime.h>
#include <hip/hip_bf16.h>

typedef __hip_bfloat16 bf16;
typedef unsigned short u16;
typedef __attribute__((ext_vector_type(8))) short bf16x8;
typedef __attribute__((ext_vector_type(4))) float f32x4;

__device__ __forceinline__ float b2f(bf16 v) { return __bfloat162float(v); }
__device__ __forceinline__ float b2f_u(u16 h) {
    union { unsigned u; float f; } c; c.u = ((unsigned)h) << 16; return c.f;
}
__device__ __forceinline__ u16 f2b(float v) {
    union { bf16 b; u16 u; } c; c.b = __float2bfloat16(v); return c.u;
}
__device__ __forceinline__ float lrelu(float v) { return v >= 0.f ? v : 0.2f * v; }
__device__ __forceinline__ float ldin(const void* p, size_t i, int isbf) {
    if (isbf) return b2f(((const bf16*)p)[i]);
    return ((const float*)p)[i];
}
// LDS tile [pl][64 ci] bf16: 128B row = 8 x 16B chunks, chunk XOR-swizzled by
// (pl&7) so both staging writes and per-lane frag reads are conflict-free.
__device__ __forceinline__ bf16x8 frag(const u16* t, int pl, int chunk) {
    return *(const bf16x8*)(t + pl * 64 + ((chunk ^ (pl & 7)) << 3));
}

// ---------------------------------------------------------------------------
// Probe: bf16 vs fp32 input detection.
// ---------------------------------------------------------------------------
__global__ __launch_bounds__(256)
void probe_kernel(const void* __restrict__ x, int* __restrict__ flag) {
    const int tid = threadIdx.x;
    __shared__ int bad;
    if (tid == 0) bad = 0;
    __syncthreads();
    const unsigned short* h = (const unsigned short*)x;
    for (int k = tid; k < 512; k += 256) {
        const unsigned e = (h[k] >> 7) & 0xFFu;
        if (e < 100u || e > 140u) atomicAdd(&bad, 1);
    }
    __syncthreads();
    if (tid == 0) flag[0] = (bad == 0) ? 1 : 0;
}

// ---------------------------------------------------------------------------
// Transpose: x [b][64ci][y][x] -> xrw [b][y][x][64ci] bf16 (raw, hi; lo plane
// in fp32 mode). LDS-transposed, all accesses vectorized + conflict-free.
// ---------------------------------------------------------------------------
__global__ __launch_bounds__(256)
void transpose_kernel(const void* __restrict__ x, u16* __restrict__ xrw,
                      u16* __restrict__ xrl, const int* __restrict__ flag) {
    __shared__ u16 hA[4096];
    __shared__ u16 lA[4096];
    const int isbf = flag[0];
    const int xb = blockIdx.x;   // 0..3
    const int y  = blockIdx.y;   // 0..255
    const int b  = blockIdx.z;   // 0..7
    const int t  = threadIdx.x;
    const int gx0 = xb << 6;

    if (isbf) {
        const u16* xp = (const u16*)x;
        for (int i = 0; i < 2; ++i) {
            const int chunk = i * 256 + t;          // 512 chunks of 8 px
            const int ci = chunk >> 3, xc = chunk & 7;
            bf16x8 v = *(const bf16x8*)(xp + (((size_t)b * 64 + ci) << 16) +
                                        ((size_t)y << 8) + gx0 + xc * 8);
#pragma unroll
            for (int j = 0; j < 8; ++j) {
                const int pl = xc * 8 + j;
                hA[pl * 64 + (ci ^ (((pl >> 3) & 7) << 3))] = (u16)v[j];
            }
        }
    } else {
        const float* xp = (const float*)x;
        for (int i = 0; i < 4; ++i) {
            const int chunk = i * 256 + t;          // 1024 chunks of 4 px
            const int ci = chunk >> 4, x4 = chunk & 15;
            f32x4 v = *(const f32x4*)(xp + (((size_t)b * 64 + ci) << 16) +
                                      ((size_t)y << 8) + gx0 + x4 * 4);
#pragma unroll
            for (int j = 0; j < 4; ++j) {
                const int pl = x4 * 4 + j;
                const int a = pl * 64 + (ci ^ (((pl >> 3) & 7) << 3));
                const u16 h = f2b(v[j]);
                hA[a] = h;
                lA[a] = f2b(v[j] - b2f_u(h));
            }
        }
    }
    __syncthreads();
    for (int i = 0; i < 2; ++i) {
        const int chunk = i * 256 + t;              // 512 chunks of 8 ci
        const int xl = chunk >> 3, co = chunk & 7;
        const int a = xl * 64 + ((co ^ ((xl >> 3) & 7)) << 3);
        const size_t dst = (((((size_t)b << 16) + ((size_t)y << 8)) + gx0 + xl) << 6) + co * 8;
        *(bf16x8*)(xrw + dst) = *(const bf16x8*)(hA + a);
        if (!isbf) *(bf16x8*)(xrl + dst) = *(const bf16x8*)(lA + a);
    }
}

// ---------------------------------------------------------------------------
// Weights: styles + demod, effective weights as INTERLEAVED bf16 hi/lo
// ([...][ci-chunk][hi x8 | lo x8]) in MFMA-A layout [b][tap][oc][ci].
// w2's ci index is fragment-permuted to match h1t's storage order.
// ---------------------------------------------------------------------------
__global__ __launch_bounds__(256)
void weights_kernel(const void* __restrict__ s,
                    const void* __restrict__ a1w, const void* __restrict__ a1b,
                    const void* __restrict__ w1,
                    const void* __restrict__ a2w, const void* __restrict__ a2b,
                    const void* __restrict__ w2,
                    const void* __restrict__ scw_in,
                    u16* __restrict__ w1x, u16* __restrict__ w2x,
                    u16* __restrict__ scx, const int* __restrict__ flag) {
    const int isbf = flag[0];
    const int b = blockIdx.x;
    const int part = blockIdx.y;   // 0..3
    const int tid = threadIdx.x;
    __shared__ float sb[64];
    __shared__ float st1[64];
    __shared__ float st2[128];
    __shared__ float d1[128];
    __shared__ float d2[128];

    if (tid < 64) sb[tid] = ldin(s, b * 64 + tid, isbf);
    __syncthreads();

    if (tid < 64) {
        float a = ldin(a1b, tid, isbf) + 1.f;
        for (int j = 0; j < 64; ++j) a += sb[j] * ldin(a1w, tid * 64 + j, isbf);
        st1[tid] = a;
    }
    if (tid >= 128) {
        const int i = tid - 128;
        float a = ldin(a2b, i, isbf) + 1.f;
        for (int j = 0; j < 64; ++j) a += sb[j] * ldin(a2w, i * 64 + j, isbf);
        st2[i] = a;
    }
    __syncthreads();

    if (tid < 128) {
        float acc = 0.f;
        if (isbf) {
            const u16* wp = (const u16*)w1 + tid * 576;
            for (int k = 0; k < 72; ++k) {
                bf16x8 v = *(const bf16x8*)(wp + k * 8);
#pragma unroll
                for (int e = 0; e < 8; ++e) {
                    const int r = k * 8 + e;
                    const float f = b2f_u((u16)v[e]) * st1[r / 9];
                    acc += f * f;
                }
            }
        } else {
            for (int i = 0; i < 64; ++i) {
                const float st = st1[i];
                for (int t = 0; t < 9; ++t) {
                    const float v = ldin(w1, (tid * 64 + i) * 9 + t, isbf) * st;
                    acc += v * v;
                }
            }
        }
        d1[tid] = rsqrtf(acc + 1e-8f);
    } else {
        const int o = tid - 128;
        float acc = 0.f;
        if (isbf) {
            const u16* wp = (const u16*)w2 + o * 1152;
            for (int k = 0; k < 144; ++k) {
                bf16x8 v = *(const bf16x8*)(wp + k * 8);
#pragma unroll
                for (int e = 0; e < 8; ++e) {
                    const int r = k * 8 + e;
                    const float f = b2f_u((u16)v[e]) * st2[r / 9];
                    acc += f * f;
                }
            }
        } else {
            for (int i = 0; i < 128; ++i) {
                const float st = st2[i];
                for (int t = 0; t < 9; ++t) {
                    const float v = ldin(w2, (o * 128 + i) * 9 + t, isbf) * st;
                    acc += v * v;
                }
            }
        }
        d2[o] = rsqrtf(acc + 1e-8f);
    }
    __syncthreads();

    // w1x: [8][9][128 oc][8 chunks][hi8|lo8]
    for (int idx = part * 18432 + tid; idx < (part + 1) * 18432; idx += 256) {
        const int o = idx / 576;
        const int r = idx - o * 576;
        const int i = r / 9;
        const int t = r - i * 9;
        const float w = ldin(w1, idx, isbf) * st1[i] * d1[o];
        const u16 h = f2b(w);
        const size_t dst = (((size_t)(b * 9 + t) * 128 + o) << 7) + ((i >> 3) << 4) + (i & 7);
        w1x[dst] = h;
        w1x[dst + 8] = f2b(w - b2f_u(h));
    }
    // w2x: [8][9][128 oc][16 chunks][hi8|lo8], ci fragment-permuted
    for (int idx = part * 36864 + tid; idx < (part + 1) * 36864; idx += 256) {
        const int o = idx / 1152;
        const int r = idx - o * 1152;
        const int i = r / 9;
        const int t = r - i * 9;
        const float w = ldin(w2, idx, isbf) * st2[i] * d2[o];
        const u16 h = f2b(w);
        const int ip = (i & 64) + (((i >> 2) & 3) << 4) + (((i >> 4) & 3) << 2) + (i & 3);
        const size_t dst = (((size_t)(b * 9 + t) * 128 + o) << 8) + ((ip >> 3) << 4) + (ip & 7);
        w2x[dst] = h;
        w2x[dst + 8] = f2b(w - b2f_u(h));
    }
    // shortcut [128 oc][8 chunks][hi8|lo8]
    if (b == 0 && part == 0) {
        for (int idx = tid; idx < 8192; idx += 256) {
            const int o = idx >> 6, i = idx & 63;
            const float w = ldin(scw_in, idx, isbf);
            const u16 h = f2b(w);
            const size_t dst = ((size_t)o << 7) + ((i >> 3) << 4) + (i & 7);
            scx[dst] = h;
            scx[dst + 8] = f2b(w - b2f_u(h));
        }
    }
}

// ---------------------------------------------------------------------------
// Conv1 (MFMA): h1 = lrelu(conv3x3(lrelu(x), w1eff) + nw*noise) -> bf16,
// stored [b][y][x][128] with fragment-permuted oc order.
// 256 thr = 4 waves (2 oc x 2 row-halves), 8x16 px tile, 23 KB LDS.
// ---------------------------------------------------------------------------
__global__ __launch_bounds__(256, 4)
void conv1_mfma(const u16* __restrict__ xrw, const u16* __restrict__ xrl,
                const void* __restrict__ noise, const void* __restrict__ nwp,
                const u16* __restrict__ w1x, u16* __restrict__ h1t,
                const int* __restrict__ flag) {
    __shared__ u16 tile[180 * 64];
    const int isbf = flag[0];
    const int n = blockIdx.x + (blockIdx.y << 4) + (blockIdx.z << 9);
    const int sw = (n & 7) * 512 + (n >> 3);         // same-b -> same XCD
    const int b = sw >> 9;
    const int by = (sw >> 4) & 31;
    const int bx = sw & 15;
    const int gx0 = bx << 4, gy0 = by << 3;
    const int tid = threadIdx.x;
    const int lane = tid & 63;
    const int wv = tid >> 6;
    const int wm = wv >> 1, wn = wv & 1;
    const int l15 = lane & 15, g = lane >> 4;

    f32x4 acc[4][4];
#pragma unroll
    for (int i = 0; i < 4; ++i)
#pragma unroll
        for (int j = 0; j < 4; ++j) acc[i][j] = (f32x4){0.f, 0.f, 0.f, 0.f};

    const u16* aBase = w1x + (size_t)b * 147456 + (wm * 64 + l15) * 128;
    const int plb = wn * 72 + l15;
    const int npass = isbf ? 1 : 2;

    for (int pass = 0; pass < npass; ++pass) {
        if (pass) __syncthreads();
        // stage lrelu(x) plane (hi on pass 0, lo on pass 1)
        for (int idx = tid; idx < 1440; idx += 256) {
            const int pl = idx >> 3, c = idx & 7;
            const int row = pl / 18, col = pl - row * 18;
            const int gy = gy0 - 1 + row, gx = gx0 - 1 + col;
            u16 outv[8];
            if ((unsigned)gy < 256u && (unsigned)gx < 256u) {
                const size_t ofs = ((((size_t)b << 16) + (gy << 8) + gx) << 6) + c * 8;
                bf16x8 vh = *(const bf16x8*)(xrw + ofs);
                if (isbf) {
#pragma unroll
                    for (int j = 0; j < 8; ++j) {
                        u16 h = (u16)vh[j];
                        if (h & 0x8000u) h = f2b(0.2f * b2f_u(h));
                        outv[j] = h;
                    }
                } else {
                    bf16x8 vl = *(const bf16x8*)(xrl + ofs);
#pragma unroll
                    for (int j = 0; j < 8; ++j) {
                        float f = lrelu(b2f_u((u16)vh[j]) + b2f_u((u16)vl[j]));
                        const u16 h = f2b(f);
                        outv[j] = (pass == 0) ? h : f2b(f - b2f_u(h));
                    }
                }
            } else {
#pragma unroll
                for (int j = 0; j < 8; ++j) outv[j] = 0;
            }
            *(bf16x8*)(tile + pl * 64 + ((c ^ (pl & 7)) << 3)) = *(bf16x8*)outv;
        }
        __syncthreads();

        const int dolo = (pass == 0);
#pragma unroll 1
        for (int kh = 0; kh < 3; ++kh) {
#pragma unroll
            for (int kw = 0; kw < 3; ++kw) {
                const int t = kh * 3 + kw;
#pragma unroll
                for (int cs = 0; cs < 2; ++cs) {
                    bf16x8 bh[4];
#pragma unroll
                    for (int fn = 0; fn < 4; ++fn)
                        bh[fn] = frag(tile, plb + (fn + kh) * 18 + kw, cs * 4 + g);
                    const u16* at = aBase + t * 16384 + (cs * 4 + g) * 16;
                    __builtin_amdgcn_s_setprio(1);
#pragma unroll
                    for (int fm = 0; fm < 4; ++fm) {
                        const bf16x8 ah = *(const bf16x8*)(at + fm * 2048);
#pragma unroll
                        for (int fn = 0; fn < 4; ++fn)
                            acc[fm][fn] = __builtin_amdgcn_mfma_f32_16x16x32_bf16(ah, bh[fn], acc[fm][fn], 0, 0, 0);
                        if (dolo) {
                            const bf16x8 al = *(const bf16x8*)(at + fm * 2048 + 8);
#pragma unroll
                            for (int fn = 0; fn < 4; ++fn)
                                acc[fm][fn] = __builtin_amdgcn_mfma_f32_16x16x32_bf16(al, bh[fn], acc[fm][fn], 0, 0, 0);
                        }
                    }
                    __builtin_amdgcn_s_setprio(0);
                }
            }
        }
    }

    const float nwv = ldin(nwp, 0, isbf);
#pragma unroll
    for (int fn = 0; fn < 4; ++fn) {
        const int gy = gy0 + wn * 4 + fn;
        const int gx = gx0 + l15;
        const float nv = nwv * ldin(noise, ((size_t)b << 16) + (gy << 8) + gx, isbf);
        unsigned wd[8];
#pragma unroll
        for (int fm = 0; fm < 4; ++fm) {
            wd[fm * 2]     = (unsigned)f2b(lrelu(acc[fm][fn][0] + nv)) |
                             ((unsigned)f2b(lrelu(acc[fm][fn][1] + nv)) << 16);
            wd[fm * 2 + 1] = (unsigned)f2b(lrelu(acc[fm][fn][2] + nv)) |
                             ((unsigned)f2b(lrelu(acc[fm][fn][3] + nv)) << 16);
        }
        // permuted slot base: wm*64 + g*16, 16 contiguous values (fm,r)
        u16* dst = h1t + ((((size_t)b << 16) + (gy << 8) + gx) << 7) + wm * 64 + g * 16;
        *(uint4*)dst = make_uint4(wd[0], wd[1], wd[2], wd[3]);
        *(uint4*)(dst + 8) = make_uint4(wd[4], wd[5], wd[6], wd[7]);
    }
}

// ---------------------------------------------------------------------------
// Conv2 (MFMA): conv3x3(h1, w2eff) + 1x1 shortcut + noise, * 1/sqrt(2).
// Chunk-at-a-time LDS (23 KB), shortcut staged from transposed raw x.
// ---------------------------------------------------------------------------
__global__ __launch_bounds__(256, 4)
void conv2_mfma(const u16* __restrict__ h1t, const u16* __restrict__ xrw,
                const u16* __restrict__ xrl,
                const void* __restrict__ noise, const void* __restrict__ nwp,
                const u16* __restrict__ w2x, const u16* __restrict__ scx,
                void* __restrict__ out, const int* __restrict__ flag) {
    __shared__ u16 tile[180 * 64];
    const int isbf = flag[0];
    const int n = blockIdx.x + (blockIdx.y << 4) + (blockIdx.z << 9);
    const int sw = (n & 7) * 512 + (n >> 3);
    const int b = sw >> 9;
    const int by = (sw >> 4) & 31;
    const int bx = sw & 15;
    const int gx0 = bx << 4, gy0 = by << 3;
    const int tid = threadIdx.x;
    const int lane = tid & 63;
    const int wv = tid >> 6;
    const int wm = wv >> 1, wn = wv & 1;
    const int l15 = lane & 15, g = lane >> 4;
    const bf16x8 z8 = {0, 0, 0, 0, 0, 0, 0, 0};

    f32x4 acc[4][4];
#pragma unroll
    for (int i = 0; i < 4; ++i)
#pragma unroll
        for (int j = 0; j < 4; ++j) acc[i][j] = (f32x4){0.f, 0.f, 0.f, 0.f};

    const int plb = wn * 72 + l15;

#pragma unroll 1
    for (int cc = 0; cc < 2; ++cc) {
        if (cc) __syncthreads();
        for (int idx = tid; idx < 1440; idx += 256) {
            const int pl = idx >> 3, c = idx & 7;
            const int row = pl / 18, col = pl - row * 18;
            const int gy = gy0 - 1 + row, gx = gx0 - 1 + col;
            bf16x8 v = z8;
            if ((unsigned)gy < 256u && (unsigned)gx < 256u)
                v = *(const bf16x8*)(h1t + ((((size_t)b << 16) + (gy << 8) + gx) << 7) + cc * 64 + c * 8);
            *(bf16x8*)(tile + pl * 64 + ((c ^ (pl & 7)) << 3)) = v;
        }
        __syncthreads();

        const u16* aBase = w2x + (size_t)b * 294912 + (wm * 64 + l15) * 256 + cc * 128;
#pragma unroll 1
        for (int kh = 0; kh < 3; ++kh) {
#pragma unroll
            for (int kw = 0; kw < 3; ++kw) {
                const int t = kh * 3 + kw;
#pragma unroll
                for (int cs = 0; cs < 2; ++cs) {
                    bf16x8 bh[4];
#pragma unroll
                    for (int fn = 0; fn < 4; ++fn)
                        bh[fn] = frag(tile, plb + (fn + kh) * 18 + kw, cs * 4 + g);
                    const u16* at = aBase + t * 32768 + (cs * 4 + g) * 16;
                    __builtin_amdgcn_s_setprio(1);
#pragma unroll
                    for (int fm = 0; fm < 4; ++fm) {
                        const bf16x8 ah = *(const bf16x8*)(at + fm * 4096);
                        const bf16x8 al = *(const bf16x8*)(at + fm * 4096 + 8);
#pragma unroll
                        for (int fn = 0; fn < 4; ++fn)
                            acc[fm][fn] = __builtin_amdgcn_mfma_f32_16x16x32_bf16(ah, bh[fn], acc[fm][fn], 0, 0, 0);
#pragma unroll
                        for (int fn = 0; fn < 4; ++fn)
                            acc[fm][fn] = __builtin_amdgcn_mfma_f32_16x16x32_bf16(al, bh[fn], acc[fm][fn], 0, 0, 0);
                    }
                    __builtin_amdgcn_s_setprio(0);
                }
            }
        }
    }

    // 1x1 shortcut on raw x (hi pass; + lo pass in fp32 mode)
    const int npass = isbf ? 1 : 2;
    for (int pass = 0; pass < npass; ++pass) {
        __syncthreads();
        for (int idx = tid; idx < 1024; idx += 256) {
            const int pl = idx >> 3, c = idx & 7;
            const int gy = gy0 + (pl >> 4), gx = gx0 + (pl & 15);
            const size_t ofs = ((((size_t)b << 16) + (gy << 8) + gx) << 6) + c * 8;
            bf16x8 v = pass ? *(const bf16x8*)(xrl + ofs) : *(const bf16x8*)(xrw + ofs);
            *(bf16x8*)(tile + pl * 64 + ((c ^ (pl & 7)) << 3)) = v;
        }
        __syncthreads();

        const u16* sBase = scx + (wm * 64 + l15) * 128;
        const int dolo = (pass == 0);
#pragma unroll
        for (int cs = 0; cs < 2; ++cs) {
            bf16x8 bh[4];
#pragma unroll
            for (int fn = 0; fn < 4; ++fn)
                bh[fn] = frag(tile, (wn * 4 + fn) * 16 + l15, cs * 4 + g);
            const u16* at = sBase + (cs * 4 + g) * 16;
            __builtin_amdgcn_s_setprio(1);
#pragma unroll
            for (int fm = 0; fm < 4; ++fm) {
                const bf16x8 ah = *(const bf16x8*)(at + fm * 2048);
#pragma unroll
                for (int fn = 0; fn < 4; ++fn)
                    acc[fm][fn] = __builtin_amdgcn_mfma_f32_16x16x32_bf16(ah, bh[fn], acc[fm][fn], 0, 0, 0);
                if (dolo) {
                    const bf16x8 al = *(const bf16x8*)(at + fm * 2048 + 8);
#pragma unroll
                    for (int fn = 0; fn < 4; ++fn)
                        acc[fm][fn] = __builtin_amdgcn_mfma_f32_16x16x32_bf16(al, bh[fn], acc[fm][fn], 0, 0, 0);
                }
            }
            __builtin_amdgcn_s_setprio(0);
        }
    }

    const float nwv = ldin(nwp, 0, isbf);
    const float kk = 0.70710678118654752f;
    if (isbf) {
        bf16* op = (bf16*)out;
#pragma unroll
        for (int fn = 0; fn < 4; ++fn) {
            const int gy = gy0 + wn * 4 + fn;
            const int gx = gx0 + l15;
            const float nv = nwv * ldin(noise, ((size_t)b << 16) + (gy << 8) + gx, isbf);
#pragma unroll
            for (int fm = 0; fm < 4; ++fm) {
                const int oc = wm * 64 + fm * 16 + g * 4;
#pragma unroll
                for (int r = 0; r < 4; ++r) {
                    const float v = (acc[fm][fn][r] + nv) * kk;
                    op[(((size_t)b * 128 + oc + r) << 16) + (gy << 8) + gx] = __float2bfloat16(v);
                }
            }
        }
    } else {
        float* op = (float*)out;
#pragma unroll
        for (int fn = 0; fn < 4; ++fn) {
            const int gy = gy0 + wn * 4 + fn;
            const int gx = gx0 + l15;
            const float nv = nwv * ldin(noise, ((size_t)b << 16) + (gy << 8) + gx, isbf);
#pragma unroll
            for (int fm = 0; fm < 4; ++fm) {
                const int oc = wm * 64 + fm * 16 + g * 4;
#pragma unroll
                for (int r = 0; r < 4; ++r) {
                    const float v = (acc[fm][fn][r] + nv) * kk;
                    op[(((size_t)b * 128 + oc + r) << 16) + (gy << 8) + gx] = v;
                }
            }
        }
    }
}

extern "C" void kernel_launch(void* const* d_in, const int* in_sizes, int n_in,
                              void* d_out, int out_size, void* d_ws, size_t ws_size,
                              hipStream_t stream) {
    const void* x     = d_in[0];
    const void* s     = d_in[1];
    const void* noise = d_in[2];
    const void* a1w   = d_in[3];
    const void* a1b   = d_in[4];
    const void* w1    = d_in[5];
    const void* a2w   = d_in[6];
    const void* a2b   = d_in[7];
    const void* w2    = d_in[8];
    const void* nw    = d_in[9];
    const void* scw   = d_in[10];

    // ws layout (bytes):
    //   flag      256
    //   w1x       2,359,296   ([8][9][128][8ch][hi8|lo8])
    //   w2x       4,718,592   ([8][9][128][16ch][hi8|lo8])
    //   scx          32,768   ([128][8ch][hi8|lo8])
    //   h1t     134,217,728   ([8][256][256][128] bf16, permuted oc)
    //   xrw      67,108,864   ([8][256][256][64] bf16, raw hi)
    //   xrl      67,108,864   (lo plane; touched only in fp32 mode)
    //   bf16-mode footprint ~208.4 MB
    char* p = (char*)d_ws;
    int* flag = (int*)p;   p += 256;
    u16* w1x = (u16*)p;    p += 2359296;
    u16* w2x = (u16*)p;    p += 4718592;
    u16* scx = (u16*)p;    p += 32768;
    u16* h1t = (u16*)p;    p += 134217728;
    u16* xrw = (u16*)p;    p += 67108864;
    u16* xrl = (u16*)p;

    probe_kernel<<<dim3(1), dim3(256), 0, stream>>>(x, flag);
    transpose_kernel<<<dim3(4, 256, 8), dim3(256), 0, stream>>>(x, xrw, xrl, flag);
    weights_kernel<<<dim3(8, 4), dim3(256), 0, stream>>>(s, a1w, a1b, w1, a2w, a2b, w2,
                                                         scw, w1x, w2x, scx, flag);
    dim3 grid(16, 32, 8);
    conv1_mfma<<<grid, dim3(256), 0, stream>>>(xrw, xrl, noise, nw, w1x, h1t, flag);
    conv2_mfma<<<grid, dim3(256), 0, stream>>>(h1t, xrw, xrl, noise, nw, w2x, scx,
                                               d_out, flag);
}

// Round 3
// 1537.576 us; speedup vs baseline: 4.0583x; 1.0867x over previous
//
#include <hip/hip_runtime.h>
#include <hip/hip_bf16.h>

typedef __hip_bfloat16 bf16;
typedef unsigned short u16;
typedef __attribute__((ext_vector_type(8))) short bf16x8;
typedef __attribute__((ext_vector_type(4))) float f32x4;

__device__ __forceinline__ float b2f(bf16 v) { return __bfloat162float(v); }
__device__ __forceinline__ float b2f_u(u16 h) {
    union { unsigned u; float f; } c; c.u = ((unsigned)h) << 16; return c.f;
}
__device__ __forceinline__ u16 f2b(float v) {
    union { bf16 b; u16 u; } c; c.b = __float2bfloat16(v); return c.u;
}
__device__ __forceinline__ float lrelu(float v) { return v >= 0.f ? v : 0.2f * v; }
__device__ __forceinline__ float ldin(const void* p, size_t i, int isbf) {
    if (isbf) return b2f(((const bf16*)p)[i]);
    return ((const float*)p)[i];
}
// LDS tile [pl][64 ci] bf16: 128B row = 8 x 16B chunks, chunk XOR-swizzled by
// (pl&7) so both staging writes and per-lane frag reads are conflict-free.
__device__ __forceinline__ bf16x8 frag(const u16* t, int pl, int chunk) {
    return *(const bf16x8*)(t + pl * 64 + ((chunk ^ (pl & 7)) << 3));
}

// ---------------------------------------------------------------------------
// Probe: bf16 vs fp32 input detection.
// ---------------------------------------------------------------------------
__global__ __launch_bounds__(256)
void probe_kernel(const void* __restrict__ x, int* __restrict__ flag) {
    const int tid = threadIdx.x;
    __shared__ int bad;
    if (tid == 0) bad = 0;
    __syncthreads();
    const unsigned short* h = (const unsigned short*)x;
    for (int k = tid; k < 512; k += 256) {
        const unsigned e = (h[k] >> 7) & 0xFFu;
        if (e < 100u || e > 140u) atomicAdd(&bad, 1);
    }
    __syncthreads();
    if (tid == 0) flag[0] = (bad == 0) ? 1 : 0;
}

// ---------------------------------------------------------------------------
// Transpose: x [b][64ci][y][x] -> xrw [b][y][x][64ci] bf16 (raw, hi; lo plane
// in fp32 mode). LDS-transposed, all accesses vectorized + conflict-free.
// ---------------------------------------------------------------------------
__global__ __launch_bounds__(256)
void transpose_kernel(const void* __restrict__ x, u16* __restrict__ xrw,
                      u16* __restrict__ xrl, const int* __restrict__ flag) {
    __shared__ u16 hA[4096];
    __shared__ u16 lA[4096];
    const int isbf = flag[0];
    const int xb = blockIdx.x;   // 0..3
    const int y  = blockIdx.y;   // 0..255
    const int b  = blockIdx.z;   // 0..7
    const int t  = threadIdx.x;
    const int gx0 = xb << 6;

    if (isbf) {
        const u16* xp = (const u16*)x;
        for (int i = 0; i < 2; ++i) {
            const int chunk = i * 256 + t;          // 512 chunks of 8 px
            const int ci = chunk >> 3, xc = chunk & 7;
            bf16x8 v = *(const bf16x8*)(xp + (((size_t)b * 64 + ci) << 16) +
                                        ((size_t)y << 8) + gx0 + xc * 8);
#pragma unroll
            for (int j = 0; j < 8; ++j) {
                const int pl = xc * 8 + j;
                hA[pl * 64 + (ci ^ (((pl >> 3) & 7) << 3))] = (u16)v[j];
            }
        }
    } else {
        const float* xp = (const float*)x;
        for (int i = 0; i < 4; ++i) {
            const int chunk = i * 256 + t;          // 1024 chunks of 4 px
            const int ci = chunk >> 4, x4 = chunk & 15;
            f32x4 v = *(const f32x4*)(xp + (((size_t)b * 64 + ci) << 16) +
                                      ((size_t)y << 8) + gx0 + x4 * 4);
#pragma unroll
            for (int j = 0; j < 4; ++j) {
                const int pl = x4 * 4 + j;
                const int a = pl * 64 + (ci ^ (((pl >> 3) & 7) << 3));
                const u16 h = f2b(v[j]);
                hA[a] = h;
                lA[a] = f2b(v[j] - b2f_u(h));
            }
        }
    }
    __syncthreads();
    for (int i = 0; i < 2; ++i) {
        const int chunk = i * 256 + t;              // 512 chunks of 8 ci
        const int xl = chunk >> 3, co = chunk & 7;
        const int a = xl * 64 + ((co ^ ((xl >> 3) & 7)) << 3);
        const size_t dst = (((((size_t)b << 16) + ((size_t)y << 8)) + gx0 + xl) << 6) + co * 8;
        *(bf16x8*)(xrw + dst) = *(const bf16x8*)(hA + a);
        if (!isbf) *(bf16x8*)(xrl + dst) = *(const bf16x8*)(lA + a);
    }
}

// ---------------------------------------------------------------------------
// Weights: styles + demod, effective weights as INTERLEAVED bf16 hi/lo
// ([...][ci-chunk][hi x8 | lo x8]) in MFMA-A layout [b][tap][oc][ci].
// w2's ci index is fragment-permuted to match h1t's storage order.
// ---------------------------------------------------------------------------
__global__ __launch_bounds__(256)
void weights_kernel(const void* __restrict__ s,
                    const void* __restrict__ a1w, const void* __restrict__ a1b,
                    const void* __restrict__ w1,
                    const void* __restrict__ a2w, const void* __restrict__ a2b,
                    const void* __restrict__ w2,
                    const void* __restrict__ scw_in,
                    u16* __restrict__ w1x, u16* __restrict__ w2x,
                    u16* __restrict__ scx, const int* __restrict__ flag) {
    const int isbf = flag[0];
    const int b = blockIdx.x;
    const int part = blockIdx.y;   // 0..3
    const int tid = threadIdx.x;
    __shared__ float sb[64];
    __shared__ float st1[64];
    __shared__ float st2[128];
    __shared__ float d1[128];
    __shared__ float d2[128];

    if (tid < 64) sb[tid] = ldin(s, b * 64 + tid, isbf);
    __syncthreads();

    if (tid < 64) {
        float a = ldin(a1b, tid, isbf) + 1.f;
        for (int j = 0; j < 64; ++j) a += sb[j] * ldin(a1w, tid * 64 + j, isbf);
        st1[tid] = a;
    }
    if (tid >= 128) {
        const int i = tid - 128;
        float a = ldin(a2b, i, isbf) + 1.f;
        for (int j = 0; j < 64; ++j) a += sb[j] * ldin(a2w, i * 64 + j, isbf);
        st2[i] = a;
    }
    __syncthreads();

    if (tid < 128) {
        float acc = 0.f;
        if (isbf) {
            const u16* wp = (const u16*)w1 + tid * 576;
            for (int k = 0; k < 72; ++k) {
                bf16x8 v = *(const bf16x8*)(wp + k * 8);
#pragma unroll
                for (int e = 0; e < 8; ++e) {
                    const int r = k * 8 + e;
                    const float f = b2f_u((u16)v[e]) * st1[r / 9];
                    acc += f * f;
                }
            }
        } else {
            for (int i = 0; i < 64; ++i) {
                const float st = st1[i];
                for (int t = 0; t < 9; ++t) {
                    const float v = ldin(w1, (tid * 64 + i) * 9 + t, isbf) * st;
                    acc += v * v;
                }
            }
        }
        d1[tid] = rsqrtf(acc + 1e-8f);
    } else {
        const int o = tid - 128;
        float acc = 0.f;
        if (isbf) {
            const u16* wp = (const u16*)w2 + o * 1152;
            for (int k = 0; k < 144; ++k) {
                bf16x8 v = *(const bf16x8*)(wp + k * 8);
#pragma unroll
                for (int e = 0; e < 8; ++e) {
                    const int r = k * 8 + e;
                    const float f = b2f_u((u16)v[e]) * st2[r / 9];
                    acc += f * f;
                }
            }
        } else {
            for (int i = 0; i < 128; ++i) {
                const float st = st2[i];
                for (int t = 0; t < 9; ++t) {
                    const float v = ldin(w2, (o * 128 + i) * 9 + t, isbf) * st;
                    acc += v * v;
                }
            }
        }
        d2[o] = rsqrtf(acc + 1e-8f);
    }
    __syncthreads();

    // w1x: [8][9][128 oc][8 chunks][hi8|lo8]
    for (int idx = part * 18432 + tid; idx < (part + 1) * 18432; idx += 256) {
        const int o = idx / 576;
        const int r = idx - o * 576;
        const int i = r / 9;
        const int t = r - i * 9;
        const float w = ldin(w1, idx, isbf) * st1[i] * d1[o];
        const u16 h = f2b(w);
        const size_t dst = (((size_t)(b * 9 + t) * 128 + o) << 7) + ((i >> 3) << 4) + (i & 7);
        w1x[dst] = h;
        w1x[dst + 8] = f2b(w - b2f_u(h));
    }
    // w2x: [8][9][128 oc][16 chunks][hi8|lo8], ci fragment-permuted
    for (int idx = part * 36864 + tid; idx < (part + 1) * 36864; idx += 256) {
        const int o = idx / 1152;
        const int r = idx - o * 1152;
        const int i = r / 9;
        const int t = r - i * 9;
        const float w = ldin(w2, idx, isbf) * st2[i] * d2[o];
        const u16 h = f2b(w);
        const int ip = (i & 64) + (((i >> 2) & 3) << 4) + (((i >> 4) & 3) << 2) + (i & 3);
        const size_t dst = (((size_t)(b * 9 + t) * 128 + o) << 8) + ((ip >> 3) << 4) + (ip & 7);
        w2x[dst] = h;
        w2x[dst + 8] = f2b(w - b2f_u(h));
    }
    // shortcut [128 oc][8 chunks][hi8|lo8]
    if (b == 0 && part == 0) {
        for (int idx = tid; idx < 8192; idx += 256) {
            const int o = idx >> 6, i = idx & 63;
            const float w = ldin(scw_in, idx, isbf);
            const u16 h = f2b(w);
            const size_t dst = ((size_t)o << 7) + ((i >> 3) << 4) + (i & 7);
            scx[dst] = h;
            scx[dst + 8] = f2b(w - b2f_u(h));
        }
    }
}

// ---------------------------------------------------------------------------
// Conv1 (MFMA, pipelined): h1 = lrelu(conv3x3(lrelu(x), w1eff) + nw*noise).
// Both activation planes staged up-front (one barrier), then a barrier-free
// fully-unrolled phase loop with one-phase-ahead A-weight register prefetch.
// ---------------------------------------------------------------------------
__global__ __launch_bounds__(256, 2)
void conv1_mfma(const u16* __restrict__ xrw, const u16* __restrict__ xrl,
                const void* __restrict__ noise, const void* __restrict__ nwp,
                const u16* __restrict__ w1x, u16* __restrict__ h1t,
                const int* __restrict__ flag) {
    __shared__ u16 lds[2 * 11520];
    u16* tile0 = lds;
    u16* tile1 = lds + 11520;
    const int isbf = flag[0];
    const int n = blockIdx.x + (blockIdx.y << 4) + (blockIdx.z << 9);
    const int sw = (n & 7) * 512 + (n >> 3);         // same-b -> same XCD
    const int b = sw >> 9;
    const int by = (sw >> 4) & 31;
    const int bx = sw & 15;
    const int gx0 = bx << 4, gy0 = by << 3;
    const int tid = threadIdx.x;
    const int lane = tid & 63;
    const int wv = tid >> 6;
    const int wm = wv >> 1, wn = wv & 1;
    const int l15 = lane & 15, g = lane >> 4;

    // ---- stage hi (and lo) planes of lrelu(x) ----
#pragma unroll
    for (int k = 0; k < 6; ++k) {
        const int idx = tid + (k << 8);
        if (idx < 1440) {
            const int pl = idx >> 3, c = idx & 7;
            const int row = pl / 18, col = pl - row * 18;
            const int gy = gy0 - 1 + row, gx = gx0 - 1 + col;
            u16 oh[8], ol[8];
            if ((unsigned)gy < 256u && (unsigned)gx < 256u) {
                const size_t ofs = ((((size_t)b << 16) + (gy << 8) + gx) << 6) + c * 8;
                bf16x8 vh = *(const bf16x8*)(xrw + ofs);
                if (isbf) {
#pragma unroll
                    for (int j = 0; j < 8; ++j) {
                        u16 h = (u16)vh[j];
                        if (h & 0x8000u) h = f2b(0.2f * b2f_u(h));
                        oh[j] = h;
                    }
                } else {
                    bf16x8 vl = *(const bf16x8*)(xrl + ofs);
#pragma unroll
                    for (int j = 0; j < 8; ++j) {
                        const float f = lrelu(b2f_u((u16)vh[j]) + b2f_u((u16)vl[j]));
                        const u16 h = f2b(f);
                        oh[j] = h;
                        ol[j] = f2b(f - b2f_u(h));
                    }
                }
            } else {
#pragma unroll
                for (int j = 0; j < 8; ++j) { oh[j] = 0; ol[j] = 0; }
            }
            const int sa = pl * 64 + ((c ^ (pl & 7)) << 3);
            *(bf16x8*)(tile0 + sa) = *(bf16x8*)oh;
            if (!isbf) *(bf16x8*)(tile1 + sa) = *(bf16x8*)ol;
        }
    }
    __syncthreads();

    f32x4 acc[4][4];
#pragma unroll
    for (int i = 0; i < 4; ++i)
#pragma unroll
        for (int j = 0; j < 4; ++j) acc[i][j] = (f32x4){0.f, 0.f, 0.f, 0.f};

    const u16* aB = w1x + (size_t)b * 147456 + (wm * 64 + l15) * 128 + g * 16;
    const int plb = wn * 72 + l15;

    auto lda = [&](bf16x8* H, bf16x8* L, int q, int dl) {
        const u16* at = aB + ((q % 18) >> 1) * 16384 + (q & 1) * 64;
#pragma unroll
        for (int fm = 0; fm < 4; ++fm) {
            H[fm] = *(const bf16x8*)(at + fm * 2048);
            if (dl) L[fm] = *(const bf16x8*)(at + fm * 2048 + 8);
        }
    };
    auto mm = [&](const bf16x8* H, const bf16x8* L, int q, int dolo) {
        const int qq = q % 18, t = qq >> 1, cs = qq & 1;
        const int kh = t / 3, kw = t - kh * 3;
        const u16* tl = (q < 18) ? tile0 : tile1;
        bf16x8 bh[4];
#pragma unroll
        for (int fn = 0; fn < 4; ++fn)
            bh[fn] = frag(tl, plb + (fn + kh) * 18 + kw, cs * 4 + g);
        __builtin_amdgcn_s_setprio(1);
#pragma unroll
        for (int fm = 0; fm < 4; ++fm) {
#pragma unroll
            for (int fn = 0; fn < 4; ++fn)
                acc[fm][fn] = __builtin_amdgcn_mfma_f32_16x16x32_bf16(H[fm], bh[fn], acc[fm][fn], 0, 0, 0);
            if (dolo) {
#pragma unroll
                for (int fn = 0; fn < 4; ++fn)
                    acc[fm][fn] = __builtin_amdgcn_mfma_f32_16x16x32_bf16(L[fm], bh[fn], acc[fm][fn], 0, 0, 0);
            }
        }
        __builtin_amdgcn_s_setprio(0);
    };

    bf16x8 Ah0[4], Al0[4], Ah1[4], Al1[4];
    lda(Ah0, Al0, 0, 1);
    if (isbf) {
#pragma unroll
        for (int q = 0; q < 18; q += 2) {
            lda(Ah1, Al1, q + 1, 1);
            mm(Ah0, Al0, q, 1);
            if (q + 2 < 18) lda(Ah0, Al0, q + 2, 1);
            mm(Ah1, Al1, q + 1, 1);
        }
    } else {
#pragma unroll
        for (int q = 0; q < 36; q += 2) {
            lda(Ah1, Al1, q + 1, (q + 1) < 18);
            mm(Ah0, Al0, q, q < 18);
            if (q + 2 < 36) lda(Ah0, Al0, q + 2, (q + 2) < 18);
            mm(Ah1, Al1, q + 1, (q + 1) < 18);
        }
    }

    const float nwv = ldin(nwp, 0, isbf);
#pragma unroll
    for (int fn = 0; fn < 4; ++fn) {
        const int gy = gy0 + wn * 4 + fn;
        const int gx = gx0 + l15;
        const float nv = nwv * ldin(noise, ((size_t)b << 16) + (gy << 8) + gx, isbf);
        unsigned wd[8];
#pragma unroll
        for (int fm = 0; fm < 4; ++fm) {
            wd[fm * 2]     = (unsigned)f2b(lrelu(acc[fm][fn][0] + nv)) |
                             ((unsigned)f2b(lrelu(acc[fm][fn][1] + nv)) << 16);
            wd[fm * 2 + 1] = (unsigned)f2b(lrelu(acc[fm][fn][2] + nv)) |
                             ((unsigned)f2b(lrelu(acc[fm][fn][3] + nv)) << 16);
        }
        // permuted slot base: wm*64 + g*16, 16 contiguous values (fm,r)
        u16* dst = h1t + ((((size_t)b << 16) + (gy << 8) + gx) << 7) + wm * 64 + g * 16;
        *(uint4*)dst = make_uint4(wd[0], wd[1], wd[2], wd[3]);
        *(uint4*)(dst + 8) = make_uint4(wd[4], wd[5], wd[6], wd[7]);
    }
}

// ---------------------------------------------------------------------------
// Conv2 (MFMA, pipelined): conv3x3(h1, w2eff) + 1x1 shortcut + noise, /sqrt2.
// Both cc-halves staged up-front (one barrier) -> 36 barrier-free phases with
// A-prefetch; shortcut x loaded issue-early/write-late (held in regs).
// ---------------------------------------------------------------------------
__global__ __launch_bounds__(256, 2)
void conv2_mfma(const u16* __restrict__ h1t, const u16* __restrict__ xrw,
                const u16* __restrict__ xrl,
                const void* __restrict__ noise, const void* __restrict__ nwp,
                const u16* __restrict__ w2x, const u16* __restrict__ scx,
                void* __restrict__ out, const int* __restrict__ flag) {
    __shared__ u16 lds[2 * 11520 + 8192];   // tile0, tile1, shortcut tile
    u16* tile0 = lds;
    u16* tile1 = lds + 11520;
    u16* tsc   = lds + 23040;
    const int isbf = flag[0];
    const int n = blockIdx.x + (blockIdx.y << 4) + (blockIdx.z << 9);
    const int sw = (n & 7) * 512 + (n >> 3);
    const int b = sw >> 9;
    const int by = (sw >> 4) & 31;
    const int bx = sw & 15;
    const int gx0 = bx << 4, gy0 = by << 3;
    const int tid = threadIdx.x;
    const int lane = tid & 63;
    const int wv = tid >> 6;
    const int wm = wv >> 1, wn = wv & 1;
    const int l15 = lane & 15, g = lane >> 4;
    const bf16x8 z8 = {0, 0, 0, 0, 0, 0, 0, 0};

    // ---- stage BOTH cc halves of h1 tile ----
    {
        bf16x8 s0[6], s1[6];
#pragma unroll
        for (int k = 0; k < 6; ++k) {
            const int idx = tid + (k << 8);
            s0[k] = z8; s1[k] = z8;
            if (idx < 1440) {
                const int pl = idx >> 3, c = idx & 7;
                const int row = pl / 18, col = pl - row * 18;
                const int gy = gy0 - 1 + row, gx = gx0 - 1 + col;
                if ((unsigned)gy < 256u && (unsigned)gx < 256u) {
                    const u16* hp = h1t + ((((size_t)b << 16) + (gy << 8) + gx) << 7) + c * 8;
                    s0[k] = *(const bf16x8*)hp;
                    s1[k] = *(const bf16x8*)(hp + 64);
                }
            }
        }
#pragma unroll
        for (int k = 0; k < 6; ++k) {
            const int idx = tid + (k << 8);
            if (idx < 1440) {
                const int pl = idx >> 3, c = idx & 7;
                const int sa = pl * 64 + ((c ^ (pl & 7)) << 3);
                *(bf16x8*)(tile0 + sa) = s0[k];
                *(bf16x8*)(tile1 + sa) = s1[k];
            }
        }
    }
    __syncthreads();

    // issue shortcut hi loads now; consumed after the conv phases
    bf16x8 sc0[4];
#pragma unroll
    for (int k = 0; k < 4; ++k) {
        const int idx = tid + (k << 8);
        const int pl = idx >> 3, c = idx & 7;
        const int gy = gy0 + (pl >> 4), gx = gx0 + (pl & 15);
        sc0[k] = *(const bf16x8*)(xrw + ((((size_t)b << 16) + (gy << 8) + gx) << 6) + c * 8);
    }

    f32x4 acc[4][4];
#pragma unroll
    for (int i = 0; i < 4; ++i)
#pragma unroll
        for (int j = 0; j < 4; ++j) acc[i][j] = (f32x4){0.f, 0.f, 0.f, 0.f};

    const u16* aB = w2x + (size_t)b * 294912 + (wm * 64 + l15) * 256 + g * 16;
    const int plb = wn * 72 + l15;

    auto lda = [&](bf16x8* H, bf16x8* L, int q) {
        const u16* at = aB + (q / 18) * 128 + ((q % 18) >> 1) * 32768 + (q & 1) * 64;
#pragma unroll
        for (int fm = 0; fm < 4; ++fm) {
            H[fm] = *(const bf16x8*)(at + fm * 4096);
            L[fm] = *(const bf16x8*)(at + fm * 4096 + 8);
        }
    };
    auto mm = [&](const bf16x8* H, const bf16x8* L, int q) {
        const int qq = q % 18, t = qq >> 1, cs = qq & 1;
        const int kh = t / 3, kw = t - kh * 3;
        const u16* tl = (q < 18) ? tile0 : tile1;
        bf16x8 bh[4];
#pragma unroll
        for (int fn = 0; fn < 4; ++fn)
            bh[fn] = frag(tl, plb + (fn + kh) * 18 + kw, cs * 4 + g);
        __builtin_amdgcn_s_setprio(1);
#pragma unroll
        for (int fm = 0; fm < 4; ++fm) {
#pragma unroll
            for (int fn = 0; fn < 4; ++fn)
                acc[fm][fn] = __builtin_amdgcn_mfma_f32_16x16x32_bf16(H[fm], bh[fn], acc[fm][fn], 0, 0, 0);
#pragma unroll
            for (int fn = 0; fn < 4; ++fn)
                acc[fm][fn] = __builtin_amdgcn_mfma_f32_16x16x32_bf16(L[fm], bh[fn], acc[fm][fn], 0, 0, 0);
        }
        __builtin_amdgcn_s_setprio(0);
    };

    {
        bf16x8 Ah0[4], Al0[4], Ah1[4], Al1[4];
        lda(Ah0, Al0, 0);
#pragma unroll
        for (int q = 0; q < 36; q += 2) {
            lda(Ah1, Al1, q + 1);
            mm(Ah0, Al0, q);
            if (q + 2 < 36) lda(Ah0, Al0, q + 2);
            mm(Ah1, Al1, q + 1);
        }
    }

    // ---- shortcut: write hi tile (loads issued long ago), compute 1x1 ----
#pragma unroll
    for (int k = 0; k < 4; ++k) {
        const int idx = tid + (k << 8);
        const int pl = idx >> 3, c = idx & 7;
        *(bf16x8*)(tsc + pl * 64 + ((c ^ (pl & 7)) << 3)) = sc0[k];
    }
    bf16x8 sc1[4];
    if (!isbf) {
#pragma unroll
        for (int k = 0; k < 4; ++k) {
            const int idx = tid + (k << 8);
            const int pl = idx >> 3, c = idx & 7;
            const int gy = gy0 + (pl >> 4), gx = gx0 + (pl & 15);
            sc1[k] = *(const bf16x8*)(xrl + ((((size_t)b << 16) + (gy << 8) + gx) << 6) + c * 8);
        }
    }
    __syncthreads();

    const u16* sB = scx + (wm * 64 + l15) * 128 + g * 16;
#pragma unroll
    for (int cs = 0; cs < 2; ++cs) {
        bf16x8 bh[4];
#pragma unroll
        for (int fn = 0; fn < 4; ++fn)
            bh[fn] = frag(tsc, (wn * 4 + fn) * 16 + l15, cs * 4 + g);
        const u16* at = sB + cs * 64;
        __builtin_amdgcn_s_setprio(1);
#pragma unroll
        for (int fm = 0; fm < 4; ++fm) {
            const bf16x8 ah = *(const bf16x8*)(at + fm * 2048);
            const bf16x8 al = *(const bf16x8*)(at + fm * 2048 + 8);
#pragma unroll
            for (int fn = 0; fn < 4; ++fn)
                acc[fm][fn] = __builtin_amdgcn_mfma_f32_16x16x32_bf16(ah, bh[fn], acc[fm][fn], 0, 0, 0);
#pragma unroll
            for (int fn = 0; fn < 4; ++fn)
                acc[fm][fn] = __builtin_amdgcn_mfma_f32_16x16x32_bf16(al, bh[fn], acc[fm][fn], 0, 0, 0);
        }
        __builtin_amdgcn_s_setprio(0);
    }
    if (!isbf) {
        // lo activation pass for the shortcut (hi weights only)
#pragma unroll
        for (int k = 0; k < 4; ++k) {
            const int idx = tid + (k << 8);
            const int pl = idx >> 3, c = idx & 7;
            *(bf16x8*)(tile0 + pl * 64 + ((c ^ (pl & 7)) << 3)) = sc1[k];
        }
        __syncthreads();
#pragma unroll
        for (int cs = 0; cs < 2; ++cs) {
            bf16x8 bh[4];
#pragma unroll
            for (int fn = 0; fn < 4; ++fn)
                bh[fn] = frag(tile0, (wn * 4 + fn) * 16 + l15, cs * 4 + g);
            const u16* at = sB + cs * 64;
            __builtin_amdgcn_s_setprio(1);
#pragma unroll
            for (int fm = 0; fm < 4; ++fm) {
                const bf16x8 ah = *(const bf16x8*)(at + fm * 2048);
#pragma unroll
                for (int fn = 0; fn < 4; ++fn)
                    acc[fm][fn] = __builtin_amdgcn_mfma_f32_16x16x32_bf16(ah, bh[fn], acc[fm][fn], 0, 0, 0);
            }
            __builtin_amdgcn_s_setprio(0);
        }
    }

    const float nwv = ldin(nwp, 0, isbf);
    const float kk = 0.70710678118654752f;
    if (isbf) {
        bf16* op = (bf16*)out;
#pragma unroll
        for (int fn = 0; fn < 4; ++fn) {
            const int gy = gy0 + wn * 4 + fn;
            const int gx = gx0 + l15;
            const float nv = nwv * ldin(noise, ((size_t)b << 16) + (gy << 8) + gx, isbf);
#pragma unroll
            for (int fm = 0; fm < 4; ++fm) {
                const int oc = wm * 64 + fm * 16 + g * 4;
#pragma unroll
                for (int r = 0; r < 4; ++r) {
                    const float v = (acc[fm][fn][r] + nv) * kk;
                    op[(((size_t)b * 128 + oc + r) << 16) + (gy << 8) + gx] = __float2bfloat16(v);
                }
            }
        }
    } else {
        float* op = (float*)out;
#pragma unroll
        for (int fn = 0; fn < 4; ++fn) {
            const int gy = gy0 + wn * 4 + fn;
            const int gx = gx0 + l15;
            const float nv = nwv * ldin(noise, ((size_t)b << 16) + (gy << 8) + gx, isbf);
#pragma unroll
            for (int fm = 0; fm < 4; ++fm) {
                const int oc = wm * 64 + fm * 16 + g * 4;
#pragma unroll
                for (int r = 0; r < 4; ++r) {
                    const float v = (acc[fm][fn][r] + nv) * kk;
                    op[(((size_t)b * 128 + oc + r) << 16) + (gy << 8) + gx] = v;
                }
            }
        }
    }
}

extern "C" void kernel_launch(void* const* d_in, const int* in_sizes, int n_in,
                              void* d_out, int out_size, void* d_ws, size_t ws_size,
                              hipStream_t stream) {
    const void* x     = d_in[0];
    const void* s     = d_in[1];
    const void* noise = d_in[2];
    const void* a1w   = d_in[3];
    const void* a1b   = d_in[4];
    const void* w1    = d_in[5];
    const void* a2w   = d_in[6];
    const void* a2b   = d_in[7];
    const void* w2    = d_in[8];
    const void* nw    = d_in[9];
    const void* scw   = d_in[10];

    // ws layout (bytes):
    //   flag      256
    //   w1x       2,359,296   ([8][9][128][8ch][hi8|lo8])
    //   w2x       4,718,592   ([8][9][128][16ch][hi8|lo8])
    //   scx          32,768   ([128][8ch][hi8|lo8])
    //   h1t     134,217,728   ([8][256][256][128] bf16, permuted oc)
    //   xrw      67,108,864   ([8][256][256][64] bf16, raw hi)
    //   xrl      67,108,864   (lo plane; touched only in fp32 mode)
    char* p = (char*)d_ws;
    int* flag = (int*)p;   p += 256;
    u16* w1x = (u16*)p;    p += 2359296;
    u16* w2x = (u16*)p;    p += 4718592;
    u16* scx = (u16*)p;    p += 32768;
    u16* h1t = (u16*)p;    p += 134217728;
    u16* xrw = (u16*)p;    p += 67108864;
    u16* xrl = (u16*)p;

    probe_kernel<<<dim3(1), dim3(256), 0, stream>>>(x, flag);
    transpose_kernel<<<dim3(4, 256, 8), dim3(256), 0, stream>>>(x, xrw, xrl, flag);
    weights_kernel<<<dim3(8, 4), dim3(256), 0, stream>>>(s, a1w, a1b, w1, a2w, a2b, w2,
                                                         scw, w1x, w2x, scx, flag);
    dim3 grid(16, 32, 8);
    conv1_mfma<<<grid, dim3(256), 0, stream>>>(xrw, xrl, noise, nw, w1x, h1t, flag);
    conv2_mfma<<<grid, dim3(256), 0, stream>>>(h1t, xrw, xrl, noise, nw, w2x, scx,
                                               d_out, flag);
}